// Round 1
// baseline (901.625 us; speedup 1.0000x reference)
//
#include <hip/hip_runtime.h>
#include <math.h>

#define HW 4096
#define CH 64
#define NCODE 1024
#define ASTR 68
#define BSTR 132
#define TAU 0.05f

// d_out layout (float elements)
#define OUT_IDX  16777216
#define OUT_LOSS 17039360
#define OUT_PERP 17039364
// ws layout (float elements)
#define WS_C2  0
#define WS_CNT 4096
#define WS_SUM 8192

// ---------------------------------------------------------------- init: c2 + zero accumulators
__global__ __launch_bounds__(256) void vq_init(const float* __restrict__ cb0, const float* __restrict__ cb1,
                                               const float* __restrict__ cb2, const float* __restrict__ cb3,
                                               float* __restrict__ ws) {
  int gid = blockIdx.x * 256 + threadIdx.x;  // 0..4095
  const float* cbs[4] = {cb0, cb1, cb2, cb3};
  const float* row = cbs[gid >> 10] + (size_t)(gid & 1023) * CH;
  float s = 0.f;
#pragma unroll
  for (int c4 = 0; c4 < 16; ++c4) {
    float4 v = *(const float4*)(row + c4 * 4);
    s += v.x * v.x + v.y * v.y + v.z * v.z + v.w * v.w;
  }
  ws[WS_C2 + gid] = s;
  ws[WS_CNT + gid] = 0.f;
  if (gid < 4) ws[WS_SUM + gid] = 0.f;
}

// ---------------------------------------------------------------- argmin: tiled distance GEMM
// block: 64 pixels x all 1024 codes (8 tiles of 128). thread tile: 4 pixels x 8 codes.
__global__ __launch_bounds__(256) void vq_argmin(
    const float* __restrict__ x,
    const float* __restrict__ cb0, const float* __restrict__ cb1,
    const float* __restrict__ cb2, const float* __restrict__ cb3,
    const float* __restrict__ ws, float* __restrict__ out) {
  __shared__ float Ash[CH][ASTR];   // [channel][pixel]
  __shared__ float Bsh[CH][BSTR];   // [channel][code]
  const int t  = threadIdx.x;
  const int tx = t & 15;            // code dim
  const int ty = t >> 4;            // pixel dim (16 groups of 4 pixels)
  const int l  = blockIdx.y;
  const float* cbs[4] = {cb0, cb1, cb2, cb3};
  const float* cb = cbs[l];
  const float* c2 = ws + WS_C2 + l * NCODE;

  const int p0  = blockIdx.x * 64;
  const int b   = p0 >> 12;
  const int hw0 = p0 & 4095;
  const float* xb = x + (size_t)(b * 256 + l * 64) * HW + hw0;

  // A tile: 64 channels x 64 pixels (global layout is already [c][pixel] -> coalesced)
#pragma unroll
  for (int i = 0; i < 4; ++i) {
    int f4 = t + i * 256;
    int c = f4 >> 4, p4 = f4 & 15;
    *(float4*)&Ash[c][p4 * 4] = *(const float4*)(xb + (size_t)c * HW + p4 * 4);
  }

  float bd1[4], bd2[4];
  int bk1[4];
#pragma unroll
  for (int p = 0; p < 4; ++p) { bd1[p] = 1e30f; bd2[p] = 1e30f; bk1[p] = 0; }

  for (int kt = 0; kt < NCODE; kt += 128) {
    __syncthreads();  // protect Bsh from previous tile's readers
    // B tile: transpose 128 codes x 64 ch -> Bsh[ch][code]
#pragma unroll
    for (int i = 0; i < 8; ++i) {
      int f4 = t + i * 256;
      int code = f4 >> 4, c4 = f4 & 15;
      float4 v = *(const float4*)(cb + (size_t)(kt + code) * CH + c4 * 4);
      Bsh[c4 * 4 + 0][code] = v.x;
      Bsh[c4 * 4 + 1][code] = v.y;
      Bsh[c4 * 4 + 2][code] = v.z;
      Bsh[c4 * 4 + 3][code] = v.w;
    }
    __syncthreads();

    float acc[4][8];
#pragma unroll
    for (int p = 0; p < 4; ++p)
#pragma unroll
      for (int j = 0; j < 8; ++j) acc[p][j] = 0.f;

#pragma unroll 4
    for (int k = 0; k < CH; ++k) {
      float4 av = *(const float4*)&Ash[k][ty * 4];
      float4 b0 = *(const float4*)&Bsh[k][tx * 4];         // codes tx*4 .. +3
      float4 b1 = *(const float4*)&Bsh[k][64 + tx * 4];    // codes 64+tx*4 .. +3
      float a[4] = {av.x, av.y, av.z, av.w};
      float bb[8] = {b0.x, b0.y, b0.z, b0.w, b1.x, b1.y, b1.z, b1.w};
#pragma unroll
      for (int p = 0; p < 4; ++p)
#pragma unroll
        for (int j = 0; j < 8; ++j)
          acc[p][j] = fmaf(a[p], bb[j], acc[p][j]);
    }

    // distances + top-2 (ascending k order within thread -> first-min tie behavior)
#pragma unroll
    for (int j = 0; j < 8; ++j) {
      int k = kt + (j < 4 ? tx * 4 + j : 64 + tx * 4 + (j - 4));
      float cc = c2[k];
#pragma unroll
      for (int p = 0; p < 4; ++p) {
        float d = fmaf(-2.f, acc[p][j], cc);  // ||f||^2 omitted: constant per row
        if (d < bd1[p])      { bd2[p] = bd1[p]; bd1[p] = d; bk1[p] = k; }
        else if (d < bd2[p]) { bd2[p] = d; }
      }
    }
  }

  // merge top-2 across the 16 tx lanes (same wave, lane groups of 16)
#pragma unroll
  for (int p = 0; p < 4; ++p) {
    float d1 = bd1[p], d2 = bd2[p];
    int k1 = bk1[p];
    for (int off = 1; off < 16; off <<= 1) {
      float od1 = __shfl_xor(d1, off);
      float od2 = __shfl_xor(d2, off);
      int   ok1 = __shfl_xor(k1, off);
      if (od1 < d1 || (od1 == d1 && ok1 < k1)) {
        d2 = fminf(d1, od2);
        d1 = od1; k1 = ok1;
      } else {
        d2 = fminf(d2, od1);
      }
    }
    if (tx == 0) {
      int pix = p0 + ty * 4 + p;
      int bb2 = pix >> 12, hw = pix & 4095;
      // near-tie -> flag for fp64 re-rank (encode as +65536)
      float enc = (float)k1 + ((d2 - d1 < TAU) ? 65536.f : 0.f);
      out[OUT_IDX + (size_t)(bb2 * 4 + l) * HW + hw] = enc;
    }
  }
}

// ---------------------------------------------------------------- fp64 re-rank of flagged rows
__global__ __launch_bounds__(64) void vq_refine(
    const float* __restrict__ x,
    const float* __restrict__ cb0, const float* __restrict__ cb1,
    const float* __restrict__ cb2, const float* __restrict__ cb3,
    float* __restrict__ out) {
  int r = blockIdx.x;  // row in indices layout: ((b*4+l)*4096 + hw)
  float v = out[OUT_IDX + r];
  if (v < 65536.f) return;  // uniform branch
  int l = (r >> 12) & 3;
  int b = r >> 14;
  int hw = r & 4095;
  const float* cbs[4] = {cb0, cb1, cb2, cb3};
  const float* cb = cbs[l];
  const float* xb = x + (size_t)(b * 256 + l * 64) * HW + hw;
  double f[CH];
#pragma unroll
  for (int c = 0; c < CH; ++c) f[c] = (double)xb[(size_t)c * HW];
  double bd = 1e300;
  int bk = 0;
  for (int j = 0; j < 16; ++j) {
    int k = threadIdx.x + j * 64;
    const float* cr = cb + (size_t)k * CH;
    double dot = 0.0, cc = 0.0;
#pragma unroll
    for (int c = 0; c < CH; ++c) {
      double cv = (double)cr[c];
      cc  = fma(cv, cv, cc);
      dot = fma(f[c], cv, dot);
    }
    double d = cc - 2.0 * dot;
    if (d < bd) { bd = d; bk = k; }
  }
  for (int off = 1; off < 64; off <<= 1) {
    double od = __shfl_xor(bd, off);
    int   ok = __shfl_xor(bk, off);
    if (od < bd || (od == bd && ok < bk)) { bd = od; bk = ok; }
  }
  if (threadIdx.x == 0) out[OUT_IDX + r] = (float)bk;
}

// ---------------------------------------------------------------- gather + MSE + histogram
__global__ __launch_bounds__(256) void vq_gather(
    const float* __restrict__ x,
    const float* __restrict__ cb0, const float* __restrict__ cb1,
    const float* __restrict__ cb2, const float* __restrict__ cb3,
    float* __restrict__ out, float* __restrict__ ws) {
  const int l = blockIdx.y;
  const int p = blockIdx.x * 256 + threadIdx.x;  // pixel within layer
  const int b = p >> 12, hw = p & 4095;
  const float* cbs[4] = {cb0, cb1, cb2, cb3};
  const int k = (int)out[OUT_IDX + (size_t)(b * 4 + l) * HW + hw];
  const float* cr = cbs[l] + (size_t)k * CH;
  const float* xb = x + (size_t)(b * 256 + l * 64) * HW + hw;
  float* qb = out + (size_t)(b * 256 + l * 64) * HW + hw;
  float ls = 0.f;
#pragma unroll
  for (int c4 = 0; c4 < 16; ++c4) {
    float4 cv = *(const float4*)(cr + c4 * 4);
    float q[4] = {cv.x, cv.y, cv.z, cv.w};
#pragma unroll
    for (int j = 0; j < 4; ++j) {
      int c = c4 * 4 + j;
      float xv = xb[(size_t)c * HW];
      qb[(size_t)c * HW] = q[j];
      float dd = q[j] - xv;
      ls = fmaf(dd, dd, ls);
    }
  }
  atomicAdd(&ws[WS_CNT + l * NCODE + k], 1.f);
  __shared__ float red[256];
  red[threadIdx.x] = ls;
  __syncthreads();
  for (int s = 128; s > 0; s >>= 1) {
    if (threadIdx.x < s) red[threadIdx.x] += red[threadIdx.x + s];
    __syncthreads();
  }
  if (threadIdx.x == 0) atomicAdd(&ws[WS_SUM + l], red[0]);
}

// ---------------------------------------------------------------- loss + perplexity
__global__ __launch_bounds__(256) void vq_final(const float* __restrict__ ws, float* __restrict__ out) {
  const int l = blockIdx.x;
  float h = 0.f;
#pragma unroll
  for (int j = 0; j < 4; ++j) {
    float cnt = ws[WS_CNT + l * NCODE + threadIdx.x + j * 256];
    float pr = cnt * (1.f / 65536.f);
    h += pr * logf(pr + 1e-10f);
  }
  __shared__ float red[256];
  red[threadIdx.x] = h;
  __syncthreads();
  for (int s = 128; s > 0; s >>= 1) {
    if (threadIdx.x < s) red[threadIdx.x] += red[threadIdx.x + s];
    __syncthreads();
  }
  if (threadIdx.x == 0) {
    out[OUT_LOSS + l] = 1.25f * ws[WS_SUM + l] / 4194304.f;
    out[OUT_PERP + l] = expf(-red[0]);
  }
}

// ---------------------------------------------------------------- launch
extern "C" void kernel_launch(void* const* d_in, const int* in_sizes, int n_in,
                              void* d_out, int out_size, void* d_ws, size_t ws_size,
                              hipStream_t stream) {
  const float* x   = (const float*)d_in[0];
  const float* cb0 = (const float*)d_in[1];
  const float* cb1 = (const float*)d_in[2];
  const float* cb2 = (const float*)d_in[3];
  const float* cb3 = (const float*)d_in[4];
  float* out = (float*)d_out;
  float* ws  = (float*)d_ws;

  vq_init  <<<dim3(16),        dim3(256), 0, stream>>>(cb0, cb1, cb2, cb3, ws);
  vq_argmin<<<dim3(1024, 4),   dim3(256), 0, stream>>>(x, cb0, cb1, cb2, cb3, ws, out);
  vq_refine<<<dim3(262144),    dim3(64),  0, stream>>>(x, cb0, cb1, cb2, cb3, out);
  vq_gather<<<dim3(256, 4),    dim3(256), 0, stream>>>(x, cb0, cb1, cb2, cb3, out, ws);
  vq_final <<<dim3(4),         dim3(256), 0, stream>>>(ws, out);
}

// Round 3
// 352.718 us; speedup vs baseline: 2.5562x; 2.5562x over previous
//
#include <hip/hip_runtime.h>
#include <math.h>

#define HW 4096
#define CH 64
#define NCODE 1024
#define TAU 0.05f
#define FLAGCAP 65536u

// d_out layout (float elements)
#define OUT_IDX  16777216
#define OUT_LOSS 17039360
#define OUT_PERP 17039364

// ws layout (float elements)
#define WS_C2    0        // [4096] f32
#define WS_CNT   4096     // [4096] f32
#define WS_SUM   8192     // [4]    f32
#define WS_FLAGC 8196     // [1]    u32
#define WS_FLAGL 8208     // [65536] u32
#define WS_CBP   73744    // cbpack: 4*1024*128 bf16 = 1 MB, 16B-aligned

typedef short bf16x8 __attribute__((ext_vector_type(8)));
typedef float f32x4v __attribute__((ext_vector_type(4)));

static __device__ __forceinline__ unsigned f2u(float f) { return __float_as_uint(f); }
static __device__ __forceinline__ float u2f(unsigned u) { return __uint_as_float(u); }
static __device__ __forceinline__ unsigned short bf16rne(float f) {
  unsigned u = f2u(f);
  unsigned r = u + 0x7FFFu + ((u >> 16) & 1u);
  return (unsigned short)(r >> 16);
}

// ---------------------------------------------------------------- prep: pack codebooks (-2*cb, RNE hi/lo split,
// frag-linear layout), c2 table, zero accumulators.
__global__ __launch_bounds__(256) void vq_prep(const float* __restrict__ cb0, const float* __restrict__ cb1,
                                               const float* __restrict__ cb2, const float* __restrict__ cb3,
                                               float* __restrict__ ws) {
  int gid = blockIdx.x * 256 + threadIdx.x;  // 0..4095 = layer*1024 + code
  int l = gid >> 10, code = gid & 1023;
  const float* cbs[4] = {cb0, cb1, cb2, cb3};
  const float* row = cbs[l] + (size_t)code * CH;

  unsigned short* cbpack = (unsigned short*)(ws + WS_CBP);
  const int kt = code >> 5, m = (code >> 4) & 1, rowc = code & 15;
  const size_t base = (size_t)l * 131072 + (size_t)kt * 4096;  // ushort offsets

  float c2 = 0.f;
#pragma unroll 8
  for (int c = 0; c < CH; ++c) {
    float v = row[c];
    c2 = fmaf(v, v, c2);
    float aa = -2.f * v;
    unsigned short ah = bf16rne(aa);
    float rest = aa - u2f((unsigned)ah << 16);   // exact (Sterbenz)
    unsigned short al = bf16rne(rest);
    // hi -> slot c ; lo -> slot 64+c ; addr(s) = base + (m*4 + s>>5)*512 + (((s>>3)&3)*16 + rowc)*8 + (s&7)
    int s0 = c, s1 = 64 + c;
    cbpack[base + (size_t)(m * 4 + (s0 >> 5)) * 512 + (size_t)(((s0 >> 3) & 3) * 16 + rowc) * 8 + (s0 & 7)] = ah;
    cbpack[base + (size_t)(m * 4 + (s1 >> 5)) * 512 + (size_t)(((s1 >> 3) & 3) * 16 + rowc) * 8 + (s1 & 7)] = al;
  }
  ws[WS_C2 + gid] = c2;
  ws[WS_CNT + gid] = 0.f;
  if (gid < 4) ws[WS_SUM + gid] = 0.f;
  if (gid == 0) *((unsigned*)(ws + WS_FLAGC)) = 0u;
}

// ---------------------------------------------------------------- argmin: MFMA distance GEMM (3-term hi/lo split)
// Block = 4 waves; wave owns 64 consecutive pixels; loops all 1024 codes. No LDS.
__global__ __launch_bounds__(256, 2) void vq_argmin(
    const float* __restrict__ x, float* __restrict__ ws, float* __restrict__ out) {
  const int layer = blockIdx.y;
  const int wid = threadIdx.x >> 6;
  const int lane = threadIdx.x & 63;
  const int rowl = lane & 15, g = lane >> 4;

  const int p0 = blockIdx.x * 256 + wid * 64;  // pixel base (within layer)
  const int b = p0 >> 12;
  const int hwb = (p0 & 4095) + rowl;
  const float* xb = x + (size_t)(b * 256 + layer * 64) * HW;

  // X frags: xf[n][chunk]; pixel = p0 + n*16 + rowl; chunks: 0=hi ch0-31, 1=hi ch32-63, 2=lo ch0-31, 3=lo ch32-63
  bf16x8 xf[4][4];
#pragma unroll
  for (int n = 0; n < 4; ++n) {
    int hw = hwb + n * 16;
#pragma unroll
    for (int j = 0; j < 8; ++j) {
      float v0 = xb[(size_t)(g * 8 + j) * HW + hw];
      float v1 = xb[(size_t)(32 + g * 8 + j) * HW + hw];
      unsigned short h0 = bf16rne(v0);
      unsigned short h1 = bf16rne(v1);
      float r0 = v0 - u2f((unsigned)h0 << 16);
      float r1 = v1 - u2f((unsigned)h1 << 16);
      xf[n][0][j] = (short)h0;
      xf[n][1][j] = (short)h1;
      xf[n][2][j] = (short)bf16rne(r0);
      xf[n][3][j] = (short)bf16rne(r1);
    }
  }

  const unsigned short* cbl = (const unsigned short*)(ws + WS_CBP) + (size_t)layer * 131072;
  const float* c2l = ws + WS_C2 + layer * NCODE;

  float d1[4], d2[4];
  int k1[4];
#pragma unroll
  for (int n = 0; n < 4; ++n) { d1[n] = 1e30f; d2[n] = 1e30f; k1[n] = 0; }

  for (int kt = 0; kt < 32; ++kt) {
    const unsigned short* cbase = cbl + (size_t)kt * 4096 + lane * 8;
#pragma unroll
    for (int m = 0; m < 2; ++m) {
      bf16x8 ch0 = *(const bf16x8*)(cbase + (m * 4 + 0) * 512);
      bf16x8 ch1 = *(const bf16x8*)(cbase + (m * 4 + 1) * 512);
      bf16x8 cl0 = *(const bf16x8*)(cbase + (m * 4 + 2) * 512);
      bf16x8 cl1 = *(const bf16x8*)(cbase + (m * 4 + 3) * 512);
      f32x4v c2v = *(const f32x4v*)(c2l + kt * 32 + m * 16 + g * 4);
      const int kb = kt * 32 + m * 16 + g * 4;
#pragma unroll
      for (int n = 0; n < 4; ++n) {
        f32x4v a = {0.f, 0.f, 0.f, 0.f};
        a = __builtin_amdgcn_mfma_f32_16x16x32_bf16(ch0, xf[n][0], a, 0, 0, 0);  // hi*hi (ch 0-31)
        a = __builtin_amdgcn_mfma_f32_16x16x32_bf16(ch1, xf[n][1], a, 0, 0, 0);  // hi*hi (ch 32-63)
        a = __builtin_amdgcn_mfma_f32_16x16x32_bf16(cl0, xf[n][0], a, 0, 0, 0);  // c_lo*x_hi
        a = __builtin_amdgcn_mfma_f32_16x16x32_bf16(cl1, xf[n][1], a, 0, 0, 0);
        a = __builtin_amdgcn_mfma_f32_16x16x32_bf16(ch0, xf[n][2], a, 0, 0, 0);  // c_hi*x_lo
        a = __builtin_amdgcn_mfma_f32_16x16x32_bf16(ch1, xf[n][3], a, 0, 0, 0);
#pragma unroll
        for (int r = 0; r < 4; ++r) {
          float d = a[r] + c2v[r];
          bool lt = d < d1[n];
          d2[n] = fminf(d2[n], fmaxf(d, d1[n]));
          d1[n] = fminf(d1[n], d);
          k1[n] = lt ? (kb + r) : k1[n];
        }
      }
    }
  }

  // merge across the 4 lane-groups (xor 16, 32); lanes g==0 write
  unsigned* flagcnt = (unsigned*)(ws + WS_FLAGC);
  unsigned* flaglist = (unsigned*)(ws + WS_FLAGL);
#pragma unroll
  for (int n = 0; n < 4; ++n) {
    float e1 = d1[n], e2 = d2[n];
    int ek = k1[n];
#pragma unroll
    for (int off = 16; off <= 32; off <<= 1) {
      float o1 = __shfl_xor(e1, off);
      float o2 = __shfl_xor(e2, off);
      int ok = __shfl_xor(ek, off);
      bool take = (o1 < e1) || (o1 == e1 && ok < ek);
      float loser = take ? e1 : o1;
      e2 = fminf(fminf(e2, o2), loser);
      e1 = take ? o1 : e1;
      ek = take ? ok : ek;
    }
    if (g == 0) {
      int p = p0 + n * 16 + rowl;
      int hw = p & 4095;
      size_t orow = (size_t)(b * 4 + layer) * HW + hw;
      out[OUT_IDX + orow] = (float)ek;
      if (e2 - e1 < TAU) {
        unsigned pos = atomicAdd(flagcnt, 1u);
        if (pos < FLAGCAP) flaglist[pos] = (unsigned)orow;
      }
    }
  }
}

// ---------------------------------------------------------------- fp64 re-rank of flagged rows (list-driven)
__global__ __launch_bounds__(64) void vq_refine(
    const float* __restrict__ x,
    const float* __restrict__ cb0, const float* __restrict__ cb1,
    const float* __restrict__ cb2, const float* __restrict__ cb3,
    const float* __restrict__ ws, float* __restrict__ out) {
  unsigned count = *((const unsigned*)(ws + WS_FLAGC));
  if (count > FLAGCAP) count = FLAGCAP;
  const unsigned* flaglist = (const unsigned*)(ws + WS_FLAGL);

  for (unsigned i = blockIdx.x; i < count; i += gridDim.x) {
    unsigned r = flaglist[i];
    int l = (r >> 12) & 3;
    int bb = r >> 14;
    int hw = r & 4095;
    const float* cb = (l == 0) ? cb0 : (l == 1) ? cb1 : (l == 2) ? cb2 : cb3;
    const float* xb = x + (size_t)(bb * 256 + l * 64) * HW + hw;
    double f[CH];
#pragma unroll
    for (int c = 0; c < CH; ++c) f[c] = (double)xb[(size_t)c * HW];
    double bd = 1e300;
    int bk = 0;
    for (int j = 0; j < 16; ++j) {
      int k = threadIdx.x + j * 64;
      const float* cr = cb + (size_t)k * CH;
      double dot = 0.0, cc = 0.0;
#pragma unroll
      for (int c = 0; c < CH; ++c) {
        double cv = (double)cr[c];
        cc = fma(cv, cv, cc);
        dot = fma(f[c], cv, dot);
      }
      double d = cc - 2.0 * dot;
      if (d < bd || (d == bd && k < bk)) { bd = d; bk = k; }
    }
    for (int off = 1; off < 64; off <<= 1) {
      double od = __shfl_xor(bd, off);
      int ok = __shfl_xor(bk, off);
      if (od < bd || (od == bd && ok < bk)) { bd = od; bk = ok; }
    }
    if (threadIdx.x == 0) out[OUT_IDX + r] = (float)bk;
  }
}

// ---------------------------------------------------------------- gather + exact MSE + LDS histogram
__global__ __launch_bounds__(256) void vq_gather(
    const float* __restrict__ x,
    const float* __restrict__ cb0, const float* __restrict__ cb1,
    const float* __restrict__ cb2, const float* __restrict__ cb3,
    float* __restrict__ out, float* __restrict__ ws) {
  __shared__ unsigned hist[NCODE];
  __shared__ float red[256];
  const int layer = blockIdx.y;
  const int t = threadIdx.x;
  const float* cb = (layer == 0) ? cb0 : (layer == 1) ? cb1 : (layer == 2) ? cb2 : cb3;

  for (int i = t; i < NCODE; i += 256) hist[i] = 0u;
  __syncthreads();

  const int pbase = blockIdx.x * 2048;
  int kk[8];
#pragma unroll
  for (int i = 0; i < 8; ++i) {
    int p = pbase + i * 256 + t;
    int bb = p >> 12, hw = p & 4095;
    int k = (int)out[OUT_IDX + (size_t)(bb * 4 + layer) * HW + hw];
    kk[i] = k;
    atomicAdd(&hist[k], 1u);
  }

  float ls = 0.f;
#pragma unroll
  for (int i = 0; i < 8; ++i) {
    int p = pbase + i * 256 + t;
    int bb = p >> 12, hw = p & 4095;
    const float* xp = x + (size_t)(bb * 256 + layer * 64) * HW + hw;
    float* qp = out + (size_t)(bb * 256 + layer * 64) * HW + hw;
    const float* cr = cb + (size_t)kk[i] * CH;
#pragma unroll
    for (int c4 = 0; c4 < 16; ++c4) {
      float4 cv = *(const float4*)(cr + c4 * 4);
      float q[4] = {cv.x, cv.y, cv.z, cv.w};
#pragma unroll
      for (int j = 0; j < 4; ++j) {
        int c = c4 * 4 + j;
        float xv = xp[(size_t)c * HW];
        qp[(size_t)c * HW] = q[j];
        float dd = q[j] - xv;
        ls = fmaf(dd, dd, ls);
      }
    }
  }

  red[t] = ls;
  __syncthreads();
  for (int s = 128; s > 0; s >>= 1) {
    if (t < s) red[t] += red[t + s];
    __syncthreads();
  }
  if (t == 0) atomicAdd(&ws[WS_SUM + layer], red[0]);

  for (int i = t; i < NCODE; i += 256) {
    unsigned h = hist[i];
    if (h) atomicAdd(&ws[WS_CNT + layer * NCODE + i], (float)h);
  }
}

// ---------------------------------------------------------------- loss + perplexity
__global__ __launch_bounds__(256) void vq_final(const float* __restrict__ ws, float* __restrict__ out) {
  const int l = blockIdx.x;
  float h = 0.f;
#pragma unroll
  for (int j = 0; j < 4; ++j) {
    float cnt = ws[WS_CNT + l * NCODE + threadIdx.x + j * 256];
    float pr = cnt * (1.f / 65536.f);
    h += pr * logf(pr + 1e-10f);
  }
  __shared__ float red[256];
  red[threadIdx.x] = h;
  __syncthreads();
  for (int s = 128; s > 0; s >>= 1) {
    if (threadIdx.x < s) red[threadIdx.x] += red[threadIdx.x + s];
    __syncthreads();
  }
  if (threadIdx.x == 0) {
    out[OUT_LOSS + l] = 1.25f * ws[WS_SUM + l] / 4194304.f;
    out[OUT_PERP + l] = expf(-red[0]);
  }
}

// ---------------------------------------------------------------- launch
extern "C" void kernel_launch(void* const* d_in, const int* in_sizes, int n_in,
                              void* d_out, int out_size, void* d_ws, size_t ws_size,
                              hipStream_t stream) {
  const float* x = (const float*)d_in[0];
  const float* cb0 = (const float*)d_in[1];
  const float* cb1 = (const float*)d_in[2];
  const float* cb2 = (const float*)d_in[3];
  const float* cb3 = (const float*)d_in[4];
  float* out = (float*)d_out;
  float* ws = (float*)d_ws;

  vq_prep  <<<dim3(16),     dim3(256), 0, stream>>>(cb0, cb1, cb2, cb3, ws);
  vq_argmin<<<dim3(256, 4), dim3(256), 0, stream>>>(x, ws, out);
  vq_refine<<<dim3(2048),   dim3(64),  0, stream>>>(x, cb0, cb1, cb2, cb3, ws, out);
  vq_gather<<<dim3(32, 4),  dim3(256), 0, stream>>>(x, cb0, cb1, cb2, cb3, out, ws);
  vq_final <<<dim3(4),      dim3(256), 0, stream>>>(ws, out);
}